// Round 8
// baseline (291.962 us; speedup 1.0000x reference)
//
#include <hip/hip_runtime.h>
#include <hip/hip_cooperative_groups.h>

#define NN 262144   // nodes
#define DD 256      // channels
#define BB 1024     // graphs
#define GEPS 1e-5f
#define NBLK 1024
#define NTHR 256
#define NWAVE ((NBLK * NTHR) / 64)   // 4096 waves
#define RPW (NN / NWAVE)             // 64 rows per wave (== 64 lanes)

typedef float floatx4 __attribute__((ext_vector_type(4)));
namespace cg = cooperative_groups;

// ws layout (floats): [0,BB)=sum, [BB,2BB)=sumsq, [2BB,3BB)=count

__device__ __forceinline__ void flush_seg(float* __restrict__ ws, int b,
                                          float s, float q, int run, int lane) {
    #pragma unroll
    for (int off = 32; off; off >>= 1) {
        s += __shfl_down(s, off, 64);
        q += __shfl_down(q, off, 64);
    }
    if (lane == 0) {
        atomicAdd(&ws[b], s);
        atomicAdd(&ws[BB + b], q);
        atomicAdd(&ws[2 * BB + b], (float)run);
    }
}

// Single cooperative kernel; stats and normalize separated by grid.sync()
// (no cross-kernel d_ws handoff — R3 showed that is unsafe under graph
// replay). Each wave owns a contiguous 64-row chunk but visits it in a
// ROTATED order (start offset g&63): value-keyed run accumulation still
// works, and at any instant the chip's active rows cover all offsets within
// every chunk -> uniform HBM channel load (R7 analysis: lockstep 256KiB-
// strided streams capped all prior variants at ~4.2 TB/s).
__global__ __launch_bounds__(NTHR, 4) void k_coop(const float4* __restrict__ x,
                                                  const int* __restrict__ batch,
                                                  const float4* __restrict__ w,
                                                  const float4* __restrict__ bi,
                                                  float4* __restrict__ out,
                                                  float* __restrict__ ws) {
    cg::grid_group grid = cg::this_grid();
    const int gtid = blockIdx.x * NTHR + threadIdx.x;
    const int gw   = gtid >> 6;        // global wave id, 0..4095
    const int lane = gtid & 63;

    // --- phase 0: zero accumulators (ws is poisoned before timing) ---
    if (gtid < 3 * BB) ws[gtid] = 0.0f;
    grid.sync();

    // --- phase 1: rotated sorted-run stats accumulation (pure read) ---
    const int r0  = gw * RPW;
    const int phi = gw & (RPW - 1);
    const int myb = batch[r0 + lane];  // 64 rows' batch ids, one per lane
    float s = 0.0f, q = 0.0f;
    int   run = 0, cur = -1;
    for (int i = 0; i < RPW; ++i) {
        const int ii = (i + phi) & (RPW - 1);
        const int b  = __shfl(myb, ii, 64);      // wave-uniform
        if (b != cur) {                          // uniform branch
            if (run) flush_seg(ws, cur, s, q, run, lane);
            cur = b; s = 0.0f; q = 0.0f; run = 0;
        }
        const float4 v = x[(r0 + ii) * 64 + lane];
        s += v.x + v.y + v.z + v.w;
        q += v.x * v.x + v.y * v.y + v.z * v.z + v.w * v.w;
        ++run;
    }
    flush_seg(ws, cur, s, q, run, lane);

    grid.sync();

    // --- phase 2: rotated normalize (L3-hot read + nt write) ---
    const float4 wv = w[lane];
    const float4 bv = bi[lane];
    float mean = 0.0f, inv = 0.0f;
    cur = -1;
    for (int i = 0; i < RPW; ++i) {
        const int ii = (i + phi) & (RPW - 1);
        const int b  = __shfl(myb, ii, 64);
        if (b != cur) {                          // uniform: reload stats
            cur = b;
            const float sum = ws[b];
            const float sq  = ws[BB + b];
            const float cn  = ws[2 * BB + b];
            const float norm = fmaxf(cn, 1.0f) * (float)DD;
            mean = sum / norm;
            const float var = fmaxf(sq / norm - mean * mean, 0.0f);
            inv = 1.0f / (sqrtf(var) + GEPS);
        }
        const int row = r0 + ii;
        const float4 v = x[row * 64 + lane];
        floatx4 o;
        o.x = (v.x - mean) * inv * wv.x + bv.x;
        o.y = (v.y - mean) * inv * wv.y + bv.y;
        o.z = (v.z - mean) * inv * wv.z + bv.z;
        o.w = (v.w - mean) * inv * wv.w + bv.w;
        __builtin_nontemporal_store(o, (floatx4*)&out[row * 64 + lane]);
    }
}

extern "C" void kernel_launch(void* const* d_in, const int* in_sizes, int n_in,
                              void* d_out, int out_size, void* d_ws, size_t ws_size,
                              hipStream_t stream) {
    const float4* x     = (const float4*)d_in[0];
    const int*    batch = (const int*)d_in[1];
    const float4* w     = (const float4*)d_in[2];
    const float4* bi    = (const float4*)d_in[3];
    float4*       out   = (float4*)d_out;
    float*        ws    = (float*)d_ws;   // 3*BB floats

    void* args[] = {(void*)&x, (void*)&batch, (void*)&w, (void*)&bi,
                    (void*)&out, (void*)&ws};
    hipLaunchCooperativeKernel((const void*)k_coop, dim3(NBLK), dim3(NTHR),
                               args, 0, stream);
}

// Round 9
// 155.171 us; speedup vs baseline: 1.8815x; 1.8815x over previous
//
#include <hip/hip_runtime.h>

#define NN 262144   // nodes
#define DD 256      // channels
#define BB 1024     // graphs
#define GEPS 1e-5f

// R9 = R5 champion (127.4 us) with ONE change: regular cached stores instead
// of __builtin_nontemporal_store. Rationale: R5 (539 MB HBM), R7 (406 MB) and
// R2 all land at 127-160 us while fillBufferAligned (plain stores) sustains
// 7 TB/s on this chip -> we are not BW/occupancy/VALU-bound; the NT store
// drain path is the prime suspect for the pass-2 throughput cap.
__global__ __launch_bounds__(1024) void k_main(const float4* __restrict__ x,
                                               const int* __restrict__ batch,
                                               const float4* __restrict__ w,
                                               const float4* __restrict__ bi,
                                               float4* __restrict__ out) {
    __shared__ int   s_coarse[2];
    __shared__ int   s_pos[2];     // each written >=once with the same value
    __shared__ float red_s[16];
    __shared__ float red_q[16];
    __shared__ float bc[2];

    const int b    = blockIdx.x;
    const int tid  = threadIdx.x;
    const int wid  = tid >> 6;     // 0..15
    const int lane = tid & 63;

    // --- phase 1: coarse lower_bound at stride 256 (targets b and b+1) ---
    if (tid < 2) s_coarse[tid] = NN;
    __syncthreads();
    {
        const int idx = tid << 8;              // 0,256,...,NN-256
        const int v   = batch[idx];
        if (v >= b)     atomicMin(&s_coarse[0], idx);
        if (v >= b + 1) atomicMin(&s_coarse[1], idx);
    }
    __syncthreads();
    // --- phase 2: exact boundary within (coarse-256, coarse] ---
    {
        const int k = tid >> 8;                // 0..3
        const int t = tid & 255;
        if (k < 2) {
            const int tgt = b + k;
            const int cc  = s_coarse[k];
            const int i   = cc - 255 + t;      // covers cc-255 .. cc
            if (i >= 0) {
                const int vi  = (i < NN) ? batch[i] : 0x7fffffff;
                const int vim = (i > 0) ? batch[i - 1] : (-2147483647 - 1);
                if (vi >= tgt && vim < tgt) s_pos[k] = i;   // unique hit
            }
        }
    }
    __syncthreads();
    const int s0 = s_pos[0];
    const int s1 = s_pos[1];
    if (s1 <= s0) return;                      // empty graph (block-uniform)

    // --- pass 1: scalar sum / sumsq over the whole segment ---
    float s = 0.0f, q = 0.0f;
    for (int r = s0 + wid; r < s1; r += 16) {
        float4 v = x[r * 64 + lane];           // 64 lanes * 16B = one 1 KiB row
        s += v.x + v.y + v.z + v.w;
        q += v.x * v.x + v.y * v.y + v.z * v.z + v.w * v.w;
    }
    #pragma unroll
    for (int off = 32; off; off >>= 1) {
        s += __shfl_down(s, off, 64);
        q += __shfl_down(q, off, 64);
    }
    if (lane == 0) { red_s[wid] = s; red_q[wid] = q; }
    __syncthreads();
    if (tid == 0) {
        float ts = 0.0f, tq = 0.0f;
        #pragma unroll
        for (int i = 0; i < 16; ++i) { ts += red_s[i]; tq += red_q[i]; }
        const float norm = (float)(s1 - s0) * (float)DD;   // deg >= 1 here
        const float mean = ts / norm;
        const float var  = fmaxf(tq / norm - mean * mean, 0.0f);
        bc[0] = mean;
        bc[1] = 1.0f / (sqrtf(var) + GEPS);
    }
    __syncthreads();
    const float  mean = bc[0];
    const float  inv  = bc[1];
    const float4 wv   = w[lane];
    const float4 bv   = bi[lane];

    // --- pass 2: normalize; x re-read L3-hot; REGULAR cached stores ---
    for (int r = s0 + wid; r < s1; r += 16) {
        float4 v = x[r * 64 + lane];
        float4 o;
        o.x = (v.x - mean) * inv * wv.x + bv.x;
        o.y = (v.y - mean) * inv * wv.y + bv.y;
        o.z = (v.z - mean) * inv * wv.z + bv.z;
        o.w = (v.w - mean) * inv * wv.w + bv.w;
        out[r * 64 + lane] = o;
    }
}

extern "C" void kernel_launch(void* const* d_in, const int* in_sizes, int n_in,
                              void* d_out, int out_size, void* d_ws, size_t ws_size,
                              hipStream_t stream) {
    const float4* x     = (const float4*)d_in[0];
    const int*    batch = (const int*)d_in[1];
    const float4* w     = (const float4*)d_in[2];
    const float4* bi    = (const float4*)d_in[3];
    float4*       out   = (float4*)d_out;

    k_main<<<BB, 1024, 0, stream>>>(x, batch, w, bi, out);
}

// Round 10
// 131.896 us; speedup vs baseline: 2.2136x; 1.1765x over previous
//
#include <hip/hip_runtime.h>

#define NN 262144   // nodes
#define DD 256      // channels
#define BB 1024     // graphs
#define GEPS 1e-5f
#define NCHUNK 16   // 16 chunks x 16 rows = 256 rows register-resident

// One block (1024 threads = 16 waves) per graph; exactly 1 block/CU at
// <=128 VGPR (compiler is forced <=128 since 16 waves must co-reside).
// Each thread holds 16 float4 = 64 data VGPRs -> 256 KiB/block genuinely
// register-resident; asm-touch pins values so the compiler cannot
// rematerialize the loads (R7 lesson: VGPR=112 proved it re-loaded).
// This removes the pass-2 re-read from the fabric (R5 analysis: 790 MB
// fabric @6.3 TB/s = 125 us; target 526 MB = ~84 us + overheads).
// Stores are CACHED: with no re-read left, L3 protection is moot and the
// cached drain path is faster (fillBuffer 7 TB/s).
__global__ __launch_bounds__(1024) void k_main(const float4* __restrict__ x,
                                               const int* __restrict__ batch,
                                               const float4* __restrict__ w,
                                               const float4* __restrict__ bi,
                                               float4* __restrict__ out) {
    __shared__ int   s_coarse[2];
    __shared__ int   s_pos[2];     // each written >=once with the same value
    __shared__ float red_s[16];
    __shared__ float red_q[16];
    __shared__ float bc[2];

    const int b    = blockIdx.x;
    const int tid  = threadIdx.x;
    const int wid  = tid >> 6;     // 0..15 = row offset within a chunk
    const int lane = tid & 63;     // float4 column within a row

    // --- segment bounds: two-phase parallel lower_bound over sorted batch ---
    if (tid < 2) s_coarse[tid] = NN;
    __syncthreads();
    {
        const int idx = tid << 8;              // 0,256,...,NN-256
        const int v   = batch[idx];
        if (v >= b)     atomicMin(&s_coarse[0], idx);
        if (v >= b + 1) atomicMin(&s_coarse[1], idx);
    }
    __syncthreads();
    {
        const int k = tid >> 8;                // 0..3
        const int t = tid & 255;
        if (k < 2) {
            const int tgt = b + k;
            const int cc  = s_coarse[k];
            const int i   = cc - 255 + t;      // covers cc-255 .. cc
            if (i >= 0) {
                const int vi  = (i < NN) ? batch[i] : 0x7fffffff;
                const int vim = (i > 0) ? batch[i - 1] : (-2147483647 - 1);
                if (vi >= tgt && vim < tgt) s_pos[k] = i;   // unique hit
            }
        }
    }
    __syncthreads();
    const int s0 = s_pos[0];
    const int s1 = s_pos[1];
    if (s1 <= s0) return;                      // empty graph (block-uniform)

    // --- pass 1: load 256 rows into registers, accumulate sum / sumsq ---
    float s = 0.0f, q = 0.0f;
    float4 v[NCHUNK];
    const int rbase = s0 + wid;
    #pragma unroll
    for (int i = 0; i < NCHUNK; ++i) {
        const int r = rbase + i * 16;          // wave-uniform guard
        if (r < s1) {
            float4 t4 = x[r * 64 + lane];
            s += t4.x + t4.y + t4.z + t4.w;
            q += t4.x * t4.x + t4.y * t4.y + t4.z * t4.z + t4.w * t4.w;
            // opaque touch: forbids rematerializing this load in pass 2
            asm volatile("" : "+v"(t4.x), "+v"(t4.y), "+v"(t4.z), "+v"(t4.w));
            v[i] = t4;
        }
    }
    // overflow rows (deg > 256): accumulate only, re-read later (L2/L3-hot)
    for (int r = rbase + NCHUNK * 16; r < s1; r += 16) {
        const float4 t4 = x[r * 64 + lane];
        s += t4.x + t4.y + t4.z + t4.w;
        q += t4.x * t4.x + t4.y * t4.y + t4.z * t4.z + t4.w * t4.w;
    }

    #pragma unroll
    for (int off = 32; off; off >>= 1) {
        s += __shfl_down(s, off, 64);
        q += __shfl_down(q, off, 64);
    }
    if (lane == 0) { red_s[wid] = s; red_q[wid] = q; }
    __syncthreads();
    if (tid == 0) {
        float ts = 0.0f, tq = 0.0f;
        #pragma unroll
        for (int i = 0; i < 16; ++i) { ts += red_s[i]; tq += red_q[i]; }
        const float norm = (float)(s1 - s0) * (float)DD;   // deg >= 1 here
        const float mean = ts / norm;
        const float var  = fmaxf(tq / norm - mean * mean, 0.0f);
        bc[0] = mean;
        bc[1] = 1.0f / (sqrtf(var) + GEPS);
    }
    __syncthreads();
    const float  mean = bc[0];
    const float  inv  = bc[1];
    const float4 wv   = w[lane];
    const float4 bv   = bi[lane];

    // --- pass 2: normalize from registers; cached write-once stream ---
    #pragma unroll
    for (int i = 0; i < NCHUNK; ++i) {
        const int r = rbase + i * 16;
        if (r < s1) {
            float4 o;
            o.x = (v[i].x - mean) * inv * wv.x + bv.x;
            o.y = (v[i].y - mean) * inv * wv.y + bv.y;
            o.z = (v[i].z - mean) * inv * wv.z + bv.z;
            o.w = (v[i].w - mean) * inv * wv.w + bv.w;
            out[r * 64 + lane] = o;
        }
    }
    for (int r = rbase + NCHUNK * 16; r < s1; r += 16) {
        const float4 t4 = x[r * 64 + lane];    // L2/L3-hot re-read
        float4 o;
        o.x = (t4.x - mean) * inv * wv.x + bv.x;
        o.y = (t4.y - mean) * inv * wv.y + bv.y;
        o.z = (t4.z - mean) * inv * wv.z + bv.z;
        o.w = (t4.w - mean) * inv * wv.w + bv.w;
        out[r * 64 + lane] = o;
    }
}

extern "C" void kernel_launch(void* const* d_in, const int* in_sizes, int n_in,
                              void* d_out, int out_size, void* d_ws, size_t ws_size,
                              hipStream_t stream) {
    const float4* x     = (const float4*)d_in[0];
    const int*    batch = (const int*)d_in[1];
    const float4* w     = (const float4*)d_in[2];
    const float4* bi    = (const float4*)d_in[3];
    float4*       out   = (float4*)d_out;

    k_main<<<BB, 1024, 0, stream>>>(x, batch, w, bi, out);
}